// Round 1
// baseline (427.258 us; speedup 1.0000x reference)
//
#include <hip/hip_runtime.h>
#include <hip/hip_bf16.h>
#include <stdint.h>

#define S_DIM 2048
#define E_DIM 2048
#define H_NUM 16
#define D_HEAD 128
#define N3E 6144

typedef __attribute__((ext_vector_type(8))) short short8;
typedef __attribute__((ext_vector_type(4))) float f32x4;
typedef __attribute__((ext_vector_type(8))) unsigned short ushort8;

__device__ __forceinline__ unsigned short f32_to_bf16_bits(float f) {
    __hip_bfloat16 b = __float2bfloat16(f);
    unsigned short u;
    __builtin_memcpy(&u, &b, 2);
    return u;
}

// ---------------- convert f32 -> bf16 (vectorized, 8 elems/thread) ----------
__global__ void k_convert(const float* __restrict__ in, __hip_bfloat16* __restrict__ out, int n) {
    int i = (blockIdx.x * 256 + threadIdx.x) * 8;
    if (i >= n) return;
    float4 a = *(const float4*)(in + i);
    float4 b = *(const float4*)(in + i + 4);
    ushort8 o;
    o[0] = f32_to_bf16_bits(a.x);
    o[1] = f32_to_bf16_bits(a.y);
    o[2] = f32_to_bf16_bits(a.z);
    o[3] = f32_to_bf16_bits(a.w);
    o[4] = f32_to_bf16_bits(b.x);
    o[5] = f32_to_bf16_bits(b.y);
    o[6] = f32_to_bf16_bits(b.z);
    o[7] = f32_to_bf16_bits(b.w);
    *(ushort8*)(out + i) = o;
}

// ------------- transpose + convert: in [R][C] f32 -> out [C][R] bf16 --------
__global__ void k_transpose_convert(const float* __restrict__ in, __hip_bfloat16* __restrict__ out,
                                    int R, int C) {
    __shared__ float tile[32][33];
    int c0 = blockIdx.x * 32, r0 = blockIdx.y * 32;
    int tx = threadIdx.x, ty = threadIdx.y;  // block (32,8)
#pragma unroll
    for (int i = 0; i < 4; ++i) {
        int r = r0 + ty + i * 8;
        tile[ty + i * 8][tx] = in[(size_t)r * C + c0 + tx];
    }
    __syncthreads();
#pragma unroll
    for (int i = 0; i < 4; ++i) {
        int c = c0 + ty + i * 8;
        out[(size_t)c * R + r0 + tx] = __float2bfloat16(tile[tx][ty + i * 8]);
    }
}

// ------------- transpose v slice of qkv (bf16): vT[hd][t] = qkv[t][4096+hd] --
__global__ void k_transpose_v(const __hip_bfloat16* __restrict__ qkv, __hip_bfloat16* __restrict__ vT) {
    __shared__ __hip_bfloat16 tile[32][33];
    int c0 = blockIdx.x * 32, t0 = blockIdx.y * 32;
    int tx = threadIdx.x, ty = threadIdx.y;  // block (32,8)
#pragma unroll
    for (int i = 0; i < 4; ++i) {
        int t = t0 + ty + i * 8;
        tile[ty + i * 8][tx] = qkv[(size_t)t * N3E + 2 * E_DIM + c0 + tx];
    }
    __syncthreads();
#pragma unroll
    for (int i = 0; i < 4; ++i) {
        int c = c0 + ty + i * 8;
        vT[(size_t)c * S_DIM + t0 + tx] = tile[tx][ty + i * 8];
    }
}

// ---------------- m97-style 128x128 bf16 GEMM, C = A * Bt^T + bias ----------
// A [M,K] bf16 row-major, Bt [N,K] bf16 row-major.
// EPI==0: outF[M,N] f32.
// EPI==1: outB[M,N] bf16 (qkv); k/v cache f32 slices written into outF at
//         offsets 4M (k) and 8M (v) floats.
template <int EPI>
__global__ __launch_bounds__(256) void k_gemm(const __hip_bfloat16* __restrict__ A,
                                              const __hip_bfloat16* __restrict__ Bt,
                                              const float* __restrict__ bias,
                                              float* __restrict__ outF,
                                              __hip_bfloat16* __restrict__ outB,
                                              int M, int N, int K) {
    __shared__ __hip_bfloat16 As[128 * 32];
    __shared__ __hip_bfloat16 Bs[128 * 32];
    const int w = threadIdx.x >> 6, lane = threadIdx.x & 63;
    const int lg = lane >> 4, l16 = lane & 15;
    const int wr = w >> 1, wc = w & 1;
    const int m0 = blockIdx.y * 128, n0 = blockIdx.x * 128;

    f32x4 acc[4][4];
#pragma unroll
    for (int i = 0; i < 4; ++i)
#pragma unroll
        for (int j = 0; j < 4; ++j) acc[i][j] = {0.f, 0.f, 0.f, 0.f};

    const int scol = (lane & 3) * 8;  // k-offset (elems) within tile row

    for (int k0 = 0; k0 < K; k0 += 32) {
#pragma unroll
        for (int j = 0; j < 2; ++j) {
            int c = w * 2 + j;                 // chunk 0..7, 16 rows each
            int row = c * 16 + (lane >> 2);    // tile row
            const __hip_bfloat16* ga = A + (size_t)(m0 + row) * K + k0 + scol;
            const __hip_bfloat16* gb = Bt + (size_t)(n0 + row) * K + k0 + scol;
            __builtin_amdgcn_global_load_lds((const __attribute__((address_space(1))) void*)ga,
                                             (__attribute__((address_space(3))) void*)(As + c * 512),
                                             16, 0, 0);
            __builtin_amdgcn_global_load_lds((const __attribute__((address_space(1))) void*)gb,
                                             (__attribute__((address_space(3))) void*)(Bs + c * 512),
                                             16, 0, 0);
        }
        __syncthreads();
        short8 af[4], bfr[4];
#pragma unroll
        for (int mi = 0; mi < 4; ++mi)
            af[mi] = *(const short8*)&As[(wr * 64 + mi * 16 + l16) * 32 + lg * 8];
#pragma unroll
        for (int ni = 0; ni < 4; ++ni)
            bfr[ni] = *(const short8*)&Bs[(wc * 64 + ni * 16 + l16) * 32 + lg * 8];
#pragma unroll
        for (int mi = 0; mi < 4; ++mi)
#pragma unroll
            for (int ni = 0; ni < 4; ++ni)
                acc[mi][ni] = __builtin_amdgcn_mfma_f32_16x16x32_bf16(af[mi], bfr[ni], acc[mi][ni], 0, 0, 0);
        __syncthreads();
    }

    const size_t OFF_K = (size_t)S_DIM * E_DIM;      // 4M floats
    const size_t OFF_V = 2 * (size_t)S_DIM * E_DIM;  // 8M floats
#pragma unroll
    for (int ni = 0; ni < 4; ++ni) {
        int jcol = n0 + wc * 64 + ni * 16 + l16;
        float bj = bias[jcol];
#pragma unroll
        for (int mi = 0; mi < 4; ++mi) {
#pragma unroll
            for (int r = 0; r < 4; ++r) {
                int s = m0 + wr * 64 + mi * 16 + lg * 4 + r;
                float v = acc[mi][ni][r] + bj;
                if (EPI == 1) {
                    outB[(size_t)s * N + jcol] = __float2bfloat16(v);
                    if (jcol >= 2 * E_DIM) {
                        outF[OFF_V + (size_t)s * E_DIM + (jcol - 2 * E_DIM)] = v;
                    } else if (jcol >= E_DIM) {
                        outF[OFF_K + (size_t)s * E_DIM + (jcol - E_DIM)] = v;
                    }
                } else {
                    outF[(size_t)s * N + jcol] = v;
                }
            }
        }
    }
}

// ---------------- flash attention (causal), one head x 64 q-rows per block --
__global__ __launch_bounds__(256) void k_attn(const __hip_bfloat16* __restrict__ qkv,  // [S][6144]
                                              const __hip_bfloat16* __restrict__ vT,   // [2048][2048] row=h*128+d
                                              __hip_bfloat16* __restrict__ concat) {   // [S][2048]
    const int h = blockIdx.y;
    const int q0 = blockIdx.x * 64;
    const int w = threadIdx.x >> 6, lane = threadIdx.x & 63;
    const int lg = lane >> 4, l16 = lane & 15;
    const int sbase = q0 + w * 16;
    const float scale = 0.08838834764831845f;  // 1/sqrt(128)

    short8 qa[4];
#pragma unroll
    for (int kc = 0; kc < 4; ++kc)
        qa[kc] = *(const short8*)&qkv[(size_t)(sbase + l16) * N3E + h * D_HEAD + kc * 32 + lg * 8];

    f32x4 O[8];
#pragma unroll
    for (int i = 0; i < 8; ++i) O[i] = {0.f, 0.f, 0.f, 0.f};
    float m_r[4], l_r[4];
#pragma unroll
    for (int r = 0; r < 4; ++r) {
        m_r[r] = -1e30f;
        l_r[r] = 0.f;
    }

    __shared__ __hip_bfloat16 plds[4][16 * 80];

    const int ntiles = q0 / 64 + 1;
    for (int it = 0; it < ntiles; ++it) {
        const int t0 = it * 64;
        const bool diag = (t0 == q0);
        f32x4 sc[4];
#pragma unroll
        for (int f = 0; f < 4; ++f) {
            sc[f] = {0.f, 0.f, 0.f, 0.f};
#pragma unroll
            for (int kc = 0; kc < 4; ++kc) {
                short8 kb = *(const short8*)&qkv[(size_t)(t0 + f * 16 + l16) * N3E + E_DIM + h * D_HEAD + kc * 32 + lg * 8];
                sc[f] = __builtin_amdgcn_mfma_f32_16x16x32_bf16(qa[kc], kb, sc[f], 0, 0, 0);
            }
        }
        float tmax[4];
#pragma unroll
        for (int r = 0; r < 4; ++r) tmax[r] = -1e30f;
#pragma unroll
        for (int f = 0; f < 4; ++f) {
#pragma unroll
            for (int r = 0; r < 4; ++r) {
                float v = sc[f][r] * scale;
                if (diag) {
                    int t = t0 + f * 16 + l16;
                    int s = sbase + lg * 4 + r;
                    if (t > s) v = -1e30f;
                }
                sc[f][r] = v;
                tmax[r] = fmaxf(tmax[r], v);
            }
        }
#pragma unroll
        for (int off = 1; off < 16; off <<= 1) {
#pragma unroll
            for (int r = 0; r < 4; ++r) tmax[r] = fmaxf(tmax[r], __shfl_xor(tmax[r], off, 64));
        }
        float alpha[4];
#pragma unroll
        for (int r = 0; r < 4; ++r) {
            float mnew = fmaxf(m_r[r], tmax[r]);
            alpha[r] = __expf(m_r[r] - mnew);
            m_r[r] = mnew;
        }
        float rsum[4] = {0.f, 0.f, 0.f, 0.f};
#pragma unroll
        for (int f = 0; f < 4; ++f) {
#pragma unroll
            for (int r = 0; r < 4; ++r) {
                float p = __expf(sc[f][r] - m_r[r]);
                sc[f][r] = p;
                rsum[r] += p;
            }
        }
#pragma unroll
        for (int off = 1; off < 16; off <<= 1) {
#pragma unroll
            for (int r = 0; r < 4; ++r) rsum[r] += __shfl_xor(rsum[r], off, 64);
        }
#pragma unroll
        for (int r = 0; r < 4; ++r) l_r[r] = l_r[r] * alpha[r] + rsum[r];
#pragma unroll
        for (int f2 = 0; f2 < 8; ++f2)
#pragma unroll
            for (int r = 0; r < 4; ++r) O[f2][r] *= alpha[r];

        // P (C-layout) -> LDS -> A-layout fragments
#pragma unroll
        for (int f = 0; f < 4; ++f)
#pragma unroll
            for (int r = 0; r < 4; ++r)
                plds[w][(lg * 4 + r) * 80 + f * 16 + l16] = __float2bfloat16(sc[f][r]);
        short8 pa[2];
#pragma unroll
        for (int tc = 0; tc < 2; ++tc)
            pa[tc] = *(const short8*)&plds[w][l16 * 80 + tc * 32 + lg * 8];

#pragma unroll
        for (int f2 = 0; f2 < 8; ++f2) {
#pragma unroll
            for (int tc = 0; tc < 2; ++tc) {
                short8 vb = *(const short8*)&vT[(size_t)(h * D_HEAD + f2 * 16 + l16) * S_DIM + t0 + tc * 32 + lg * 8];
                O[f2] = __builtin_amdgcn_mfma_f32_16x16x32_bf16(pa[tc], vb, O[f2], 0, 0, 0);
            }
        }
    }

#pragma unroll
    for (int f2 = 0; f2 < 8; ++f2) {
#pragma unroll
        for (int r = 0; r < 4; ++r) {
            int s = sbase + lg * 4 + r;
            float v = O[f2][r] / l_r[r];
            concat[(size_t)s * E_DIM + h * D_HEAD + f2 * 16 + l16] = __float2bfloat16(v);
        }
    }
}

extern "C" void kernel_launch(void* const* d_in, const int* in_sizes, int n_in,
                              void* d_out, int out_size, void* d_ws, size_t ws_size,
                              hipStream_t stream) {
    const float* x = (const float*)d_in[0];
    const float* W_attn = (const float*)d_in[1];
    const float* b_attn = (const float*)d_in[2];
    const float* W_proj = (const float*)d_in[3];
    const float* b_proj = (const float*)d_in[4];
    float* out = (float*)d_out;

    // workspace layout (bf16 buffers); concat aliases xb (xb dead after GEMM1)
    __hip_bfloat16* xb = (__hip_bfloat16*)d_ws;                    // 2048x2048
    __hip_bfloat16* WaT = xb + (size_t)S_DIM * E_DIM;              // 6144x2048
    __hip_bfloat16* WpT = WaT + (size_t)N3E * E_DIM;               // 2048x2048
    __hip_bfloat16* qkvb = WpT + (size_t)E_DIM * E_DIM;            // 2048x6144
    __hip_bfloat16* vT = qkvb + (size_t)S_DIM * N3E;               // 2048x2048
    __hip_bfloat16* concat = xb;                                   // alias

    // 1. convert x to bf16
    k_convert<<<dim3((S_DIM * E_DIM) / (256 * 8)), dim3(256), 0, stream>>>(x, xb, S_DIM * E_DIM);
    // 2. W_attn [2048][6144] -> WaT [6144][2048] bf16
    k_transpose_convert<<<dim3(N3E / 32, E_DIM / 32), dim3(32, 8), 0, stream>>>(W_attn, WaT, E_DIM, N3E);
    // 3. W_proj [2048][2048] -> WpT [2048][2048] bf16
    k_transpose_convert<<<dim3(E_DIM / 32, E_DIM / 32), dim3(32, 8), 0, stream>>>(W_proj, WpT, E_DIM, E_DIM);
    // 4. GEMM1: qkv = x @ W_attn + b_attn (writes k/v caches f32 + qkv bf16)
    k_gemm<1><<<dim3(N3E / 128, S_DIM / 128), dim3(256), 0, stream>>>(xb, WaT, b_attn, out, qkvb,
                                                                      S_DIM, N3E, E_DIM);
    // 5. transpose V slice -> vT
    k_transpose_v<<<dim3(E_DIM / 32, S_DIM / 32), dim3(32, 8), 0, stream>>>(qkvb, vT);
    // 6. attention -> concat (bf16)
    k_attn<<<dim3(S_DIM / 64, H_NUM), dim3(256), 0, stream>>>(qkvb, vT, concat);
    // 7. GEMM2: out = concat @ W_proj + b_proj
    k_gemm<0><<<dim3(E_DIM / 128, S_DIM / 128), dim3(256), 0, stream>>>(concat, WpT, b_proj, out,
                                                                        nullptr, S_DIM, E_DIM, E_DIM);
}

// Round 2
// 271.921 us; speedup vs baseline: 1.5713x; 1.5713x over previous
//
#include <hip/hip_runtime.h>
#include <hip/hip_bf16.h>
#include <stdint.h>

#define S_DIM 2048
#define E_DIM 2048
#define H_NUM 16
#define D_HEAD 128
#define N3E 6144

typedef __attribute__((ext_vector_type(8))) short short8;
typedef __attribute__((ext_vector_type(4))) float f32x4;
typedef __attribute__((ext_vector_type(8))) unsigned short ushort8;

__device__ __forceinline__ unsigned short f32_to_bf16_bits(float f) {
    __hip_bfloat16 b = __float2bfloat16(f);
    unsigned short u;
    __builtin_memcpy(&u, &b, 2);
    return u;
}

// ---------------- convert f32 -> bf16 (vectorized, 8 elems/thread) ----------
__global__ void k_convert(const float* __restrict__ in, __hip_bfloat16* __restrict__ out, int n) {
    int i = (blockIdx.x * 256 + threadIdx.x) * 8;
    if (i >= n) return;
    float4 a = *(const float4*)(in + i);
    float4 b = *(const float4*)(in + i + 4);
    ushort8 o;
    o[0] = f32_to_bf16_bits(a.x);
    o[1] = f32_to_bf16_bits(a.y);
    o[2] = f32_to_bf16_bits(a.z);
    o[3] = f32_to_bf16_bits(a.w);
    o[4] = f32_to_bf16_bits(b.x);
    o[5] = f32_to_bf16_bits(b.y);
    o[6] = f32_to_bf16_bits(b.z);
    o[7] = f32_to_bf16_bits(b.w);
    *(ushort8*)(out + i) = o;
}

// ------------- transpose + convert: in [R][C] f32 -> out [C][R] bf16 --------
__global__ void k_transpose_convert(const float* __restrict__ in, __hip_bfloat16* __restrict__ out,
                                    int R, int C) {
    __shared__ float tile[32][33];
    int c0 = blockIdx.x * 32, r0 = blockIdx.y * 32;
    int tx = threadIdx.x, ty = threadIdx.y;  // block (32,8)
#pragma unroll
    for (int i = 0; i < 4; ++i) {
        int r = r0 + ty + i * 8;
        tile[ty + i * 8][tx] = in[(size_t)r * C + c0 + tx];
    }
    __syncthreads();
#pragma unroll
    for (int i = 0; i < 4; ++i) {
        int c = c0 + ty + i * 8;
        out[(size_t)c * R + r0 + tx] = __float2bfloat16(tile[tx][ty + i * 8]);
    }
}

// ------------- transpose v slice of qkv (bf16): vT[hd][t] = qkv[t][4096+hd] --
__global__ void k_transpose_v(const __hip_bfloat16* __restrict__ qkv, __hip_bfloat16* __restrict__ vT) {
    __shared__ __hip_bfloat16 tile[32][33];
    int c0 = blockIdx.x * 32, t0 = blockIdx.y * 32;
    int tx = threadIdx.x, ty = threadIdx.y;  // block (32,8)
#pragma unroll
    for (int i = 0; i < 4; ++i) {
        int t = t0 + ty + i * 8;
        tile[ty + i * 8][tx] = qkv[(size_t)t * N3E + 2 * E_DIM + c0 + tx];
    }
    __syncthreads();
#pragma unroll
    for (int i = 0; i < 4; ++i) {
        int c = c0 + ty + i * 8;
        vT[(size_t)c * S_DIM + t0 + tx] = tile[tx][ty + i * 8];
    }
}

// ---------------- m97-style 128x128 bf16 GEMM, C = A * Bt^T + bias ----------
template <int EPI>
__global__ __launch_bounds__(256) void k_gemm(const __hip_bfloat16* __restrict__ A,
                                              const __hip_bfloat16* __restrict__ Bt,
                                              const float* __restrict__ bias,
                                              float* __restrict__ outF,
                                              __hip_bfloat16* __restrict__ outB,
                                              int M, int N, int K) {
    __shared__ __hip_bfloat16 As[128 * 32];
    __shared__ __hip_bfloat16 Bs[128 * 32];
    const int w = threadIdx.x >> 6, lane = threadIdx.x & 63;
    const int lg = lane >> 4, l16 = lane & 15;
    const int wr = w >> 1, wc = w & 1;
    const int m0 = blockIdx.y * 128, n0 = blockIdx.x * 128;

    f32x4 acc[4][4];
#pragma unroll
    for (int i = 0; i < 4; ++i)
#pragma unroll
        for (int j = 0; j < 4; ++j) acc[i][j] = {0.f, 0.f, 0.f, 0.f};

    const int scol = (lane & 3) * 8;

    for (int k0 = 0; k0 < K; k0 += 32) {
#pragma unroll
        for (int j = 0; j < 2; ++j) {
            int c = w * 2 + j;
            int row = c * 16 + (lane >> 2);
            const __hip_bfloat16* ga = A + (size_t)(m0 + row) * K + k0 + scol;
            const __hip_bfloat16* gb = Bt + (size_t)(n0 + row) * K + k0 + scol;
            __builtin_amdgcn_global_load_lds((const __attribute__((address_space(1))) void*)ga,
                                             (__attribute__((address_space(3))) void*)(As + c * 512),
                                             16, 0, 0);
            __builtin_amdgcn_global_load_lds((const __attribute__((address_space(1))) void*)gb,
                                             (__attribute__((address_space(3))) void*)(Bs + c * 512),
                                             16, 0, 0);
        }
        __syncthreads();
        short8 af[4], bfr[4];
#pragma unroll
        for (int mi = 0; mi < 4; ++mi)
            af[mi] = *(const short8*)&As[(wr * 64 + mi * 16 + l16) * 32 + lg * 8];
#pragma unroll
        for (int ni = 0; ni < 4; ++ni)
            bfr[ni] = *(const short8*)&Bs[(wc * 64 + ni * 16 + l16) * 32 + lg * 8];
#pragma unroll
        for (int mi = 0; mi < 4; ++mi)
#pragma unroll
            for (int ni = 0; ni < 4; ++ni)
                acc[mi][ni] = __builtin_amdgcn_mfma_f32_16x16x32_bf16(af[mi], bfr[ni], acc[mi][ni], 0, 0, 0);
        __syncthreads();
    }

    const size_t OFF_K = (size_t)S_DIM * E_DIM;
    const size_t OFF_V = 2 * (size_t)S_DIM * E_DIM;
#pragma unroll
    for (int ni = 0; ni < 4; ++ni) {
        int jcol = n0 + wc * 64 + ni * 16 + l16;
        float bj = bias[jcol];
#pragma unroll
        for (int mi = 0; mi < 4; ++mi) {
#pragma unroll
            for (int r = 0; r < 4; ++r) {
                int s = m0 + wr * 64 + mi * 16 + lg * 4 + r;
                float v = acc[mi][ni][r] + bj;
                if (EPI == 1) {
                    outB[(size_t)s * N + jcol] = __float2bfloat16(v);
                    if (jcol >= 2 * E_DIM) {
                        outF[OFF_V + (size_t)s * E_DIM + (jcol - 2 * E_DIM)] = v;
                    } else if (jcol >= E_DIM) {
                        outF[OFF_K + (size_t)s * E_DIM + (jcol - E_DIM)] = v;
                    }
                } else {
                    outF[(size_t)s * N + jcol] = v;
                }
            }
        }
    }
}

// ---------------- flash attention (causal), one head x 64 q-rows per block --
// LDS-staged K/V tiles, double-buffered, one barrier per tile.
// K tile Ks[64][128] and V tile Vs[128][64] are XOR-swizzled:
//   stored LDS 16B-slot = logical 16B-slot ^ (row&7)
// Achieved with linear global_load_lds dest + inverse-swizzled GLOBAL source,
// and the same XOR applied on ds_read (guide rule #21 / G4).
__global__ __launch_bounds__(256) void k_attn(const __hip_bfloat16* __restrict__ qkv,  // [S][6144]
                                              const __hip_bfloat16* __restrict__ vT,   // [2048][2048] row=h*128+d
                                              __hip_bfloat16* __restrict__ concat) {   // [S][2048]
    const int h = blockIdx.y;
    const int q0 = blockIdx.x * 64;
    const int tid = threadIdx.x;
    const int w = tid >> 6, lane = tid & 63;
    const int lg = lane >> 4, l16 = lane & 15;
    const int sbase = q0 + w * 16;
    const float scale = 0.08838834764831845f;  // 1/sqrt(128)

    __shared__ __hip_bfloat16 Ks[2][64 * 128];   // [t][d], swizzled
    __shared__ __hip_bfloat16 Vs[2][128 * 64];   // [d][t], swizzled
    __shared__ __hip_bfloat16 plds[4][16 * 80];

    // Q fragments (global, once per block; L2-resident)
    short8 qa[4];
#pragma unroll
    for (int kc = 0; kc < 4; ++kc)
        qa[kc] = *(const short8*)&qkv[(size_t)(sbase + l16) * N3E + h * D_HEAD + kc * 32 + lg * 8];

    f32x4 O[8];
#pragma unroll
    for (int i = 0; i < 8; ++i) O[i] = {0.f, 0.f, 0.f, 0.f};
    float m_r[4], l_r[4];
#pragma unroll
    for (int r = 0; r < 4; ++r) {
        m_r[r] = -1e30f;
        l_r[r] = 0.f;
    }

    // cooperative stage of one K/V tile pair into buffer `buf`
    auto stage = [&](int buf, int t0) {
#pragma unroll
        for (int j = 0; j < 4; ++j) {
            // K: 16 rows x 256B per issue
            int kr = j * 16 + w * 4 + (lane >> 4);          // tile row 0..63
            int ks16 = (lane & 15) ^ (kr & 7);              // inverse-swizzled 16B slot
            const __hip_bfloat16* gk = qkv + (size_t)(t0 + kr) * N3E + E_DIM + h * D_HEAD + ks16 * 8;
            __builtin_amdgcn_global_load_lds((const __attribute__((address_space(1))) void*)gk,
                                             (__attribute__((address_space(3))) void*)(&Ks[buf][j * 2048 + w * 512]),
                                             16, 0, 0);
            // V: 32 rows x 128B per issue
            int vd = j * 32 + w * 8 + (lane >> 3);          // d 0..127
            int vs16 = (lane & 7) ^ (vd & 7);
            const __hip_bfloat16* gv = vT + (size_t)(h * D_HEAD + vd) * S_DIM + t0 + vs16 * 8;
            __builtin_amdgcn_global_load_lds((const __attribute__((address_space(1))) void*)gv,
                                             (__attribute__((address_space(3))) void*)(&Vs[buf][j * 2048 + w * 512]),
                                             16, 0, 0);
        }
    };

    const int ntiles = q0 / 64 + 1;
    stage(0, 0);
    int cur = 0;

    for (int it = 0; it < ntiles; ++it) {
        const int t0 = it * 64;
        __syncthreads();  // vmcnt drained here -> buf[cur] ready; prev compute done everywhere
        if (it + 1 < ntiles) stage(cur ^ 1, (it + 1) * 64);  // overlaps with compute below
        const bool diag = (t0 == q0);

        // ---- QK^T from LDS (swizzled reads) ----
        f32x4 sc[4];
#pragma unroll
        for (int f = 0; f < 4; ++f) {
            sc[f] = {0.f, 0.f, 0.f, 0.f};
            int r = f * 16 + l16;
#pragma unroll
            for (int kc = 0; kc < 4; ++kc) {
                int ce = (kc * 32 + lg * 8) ^ ((r & 7) << 3);
                short8 kb = *(const short8*)&Ks[cur][r * 128 + ce];
                sc[f] = __builtin_amdgcn_mfma_f32_16x16x32_bf16(qa[kc], kb, sc[f], 0, 0, 0);
            }
        }

        // ---- online softmax ----
        float tmax[4];
#pragma unroll
        for (int r = 0; r < 4; ++r) tmax[r] = -1e30f;
#pragma unroll
        for (int f = 0; f < 4; ++f) {
#pragma unroll
            for (int r = 0; r < 4; ++r) {
                float v = sc[f][r] * scale;
                if (diag) {
                    int t = t0 + f * 16 + l16;
                    int s = sbase + lg * 4 + r;
                    if (t > s) v = -1e30f;
                }
                sc[f][r] = v;
                tmax[r] = fmaxf(tmax[r], v);
            }
        }
#pragma unroll
        for (int off = 1; off < 16; off <<= 1) {
#pragma unroll
            for (int r = 0; r < 4; ++r) tmax[r] = fmaxf(tmax[r], __shfl_xor(tmax[r], off, 64));
        }
        float alpha[4];
#pragma unroll
        for (int r = 0; r < 4; ++r) {
            float mnew = fmaxf(m_r[r], tmax[r]);
            alpha[r] = __expf(m_r[r] - mnew);
            m_r[r] = mnew;
        }
        float rsum[4] = {0.f, 0.f, 0.f, 0.f};
#pragma unroll
        for (int f = 0; f < 4; ++f) {
#pragma unroll
            for (int r = 0; r < 4; ++r) {
                float p = __expf(sc[f][r] - m_r[r]);
                sc[f][r] = p;
                rsum[r] += p;
            }
        }
#pragma unroll
        for (int off = 1; off < 16; off <<= 1) {
#pragma unroll
            for (int r = 0; r < 4; ++r) rsum[r] += __shfl_xor(rsum[r], off, 64);
        }
#pragma unroll
        for (int r = 0; r < 4; ++r) l_r[r] = l_r[r] * alpha[r] + rsum[r];
#pragma unroll
        for (int f2 = 0; f2 < 8; ++f2)
#pragma unroll
            for (int r = 0; r < 4; ++r) O[f2][r] *= alpha[r];

        // ---- P (C-layout) -> LDS -> A-layout fragments ----
#pragma unroll
        for (int f = 0; f < 4; ++f)
#pragma unroll
            for (int r = 0; r < 4; ++r)
                plds[w][(lg * 4 + r) * 80 + f * 16 + l16] = __float2bfloat16(sc[f][r]);
        short8 pa[2];
#pragma unroll
        for (int tc = 0; tc < 2; ++tc)
            pa[tc] = *(const short8*)&plds[w][l16 * 80 + tc * 32 + lg * 8];

        // ---- PV from LDS (swizzled reads) ----
#pragma unroll
        for (int f2 = 0; f2 < 8; ++f2) {
            int d = f2 * 16 + l16;
#pragma unroll
            for (int tc = 0; tc < 2; ++tc) {
                int ce = (tc * 32 + lg * 8) ^ ((d & 7) << 3);
                short8 vb = *(const short8*)&Vs[cur][d * 64 + ce];
                O[f2] = __builtin_amdgcn_mfma_f32_16x16x32_bf16(pa[tc], vb, O[f2], 0, 0, 0);
            }
        }
        cur ^= 1;
    }

#pragma unroll
    for (int f2 = 0; f2 < 8; ++f2) {
#pragma unroll
        for (int r = 0; r < 4; ++r) {
            int s = sbase + lg * 4 + r;
            float v = O[f2][r] / l_r[r];
            concat[(size_t)s * E_DIM + h * D_HEAD + f2 * 16 + l16] = __float2bfloat16(v);
        }
    }
}

extern "C" void kernel_launch(void* const* d_in, const int* in_sizes, int n_in,
                              void* d_out, int out_size, void* d_ws, size_t ws_size,
                              hipStream_t stream) {
    const float* x = (const float*)d_in[0];
    const float* W_attn = (const float*)d_in[1];
    const float* b_attn = (const float*)d_in[2];
    const float* W_proj = (const float*)d_in[3];
    const float* b_proj = (const float*)d_in[4];
    float* out = (float*)d_out;

    __hip_bfloat16* xb = (__hip_bfloat16*)d_ws;                    // 2048x2048
    __hip_bfloat16* WaT = xb + (size_t)S_DIM * E_DIM;              // 6144x2048
    __hip_bfloat16* WpT = WaT + (size_t)N3E * E_DIM;               // 2048x2048
    __hip_bfloat16* qkvb = WpT + (size_t)E_DIM * E_DIM;            // 2048x6144
    __hip_bfloat16* vT = qkvb + (size_t)S_DIM * N3E;               // 2048x2048
    __hip_bfloat16* concat = xb;                                   // alias

    k_convert<<<dim3((S_DIM * E_DIM) / (256 * 8)), dim3(256), 0, stream>>>(x, xb, S_DIM * E_DIM);
    k_transpose_convert<<<dim3(N3E / 32, E_DIM / 32), dim3(32, 8), 0, stream>>>(W_attn, WaT, E_DIM, N3E);
    k_transpose_convert<<<dim3(E_DIM / 32, E_DIM / 32), dim3(32, 8), 0, stream>>>(W_proj, WpT, E_DIM, E_DIM);
    k_gemm<1><<<dim3(N3E / 128, S_DIM / 128), dim3(256), 0, stream>>>(xb, WaT, b_attn, out, qkvb,
                                                                      S_DIM, N3E, E_DIM);
    k_transpose_v<<<dim3(E_DIM / 32, S_DIM / 32), dim3(32, 8), 0, stream>>>(qkvb, vT);
    k_attn<<<dim3(S_DIM / 64, H_NUM), dim3(256), 0, stream>>>(qkvb, vT, concat);
    k_gemm<0><<<dim3(E_DIM / 128, S_DIM / 128), dim3(256), 0, stream>>>(concat, WpT, b_proj, out,
                                                                        nullptr, S_DIM, E_DIM, E_DIM);
}

// Round 3
// 240.896 us; speedup vs baseline: 1.7736x; 1.1288x over previous
//
#include <hip/hip_runtime.h>
#include <hip/hip_bf16.h>
#include <stdint.h>

#define S_DIM 2048
#define E_DIM 2048
#define H_NUM 16
#define D_HEAD 128
#define N3E 6144

typedef __attribute__((ext_vector_type(8))) short short8;
typedef __attribute__((ext_vector_type(4))) float f32x4;
typedef __attribute__((ext_vector_type(8))) unsigned short ushort8;

__device__ __forceinline__ unsigned short f32_to_bf16_bits(float f) {
    __hip_bfloat16 b = __float2bfloat16(f);
    unsigned short u;
    __builtin_memcpy(&u, &b, 2);
    return u;
}

// ---------------- convert f32 -> bf16 (vectorized, 8 elems/thread) ----------
__global__ void k_convert(const float* __restrict__ in, __hip_bfloat16* __restrict__ out, int n) {
    int i = (blockIdx.x * 256 + threadIdx.x) * 8;
    if (i >= n) return;
    float4 a = *(const float4*)(in + i);
    float4 b = *(const float4*)(in + i + 4);
    ushort8 o;
    o[0] = f32_to_bf16_bits(a.x);
    o[1] = f32_to_bf16_bits(a.y);
    o[2] = f32_to_bf16_bits(a.z);
    o[3] = f32_to_bf16_bits(a.w);
    o[4] = f32_to_bf16_bits(b.x);
    o[5] = f32_to_bf16_bits(b.y);
    o[6] = f32_to_bf16_bits(b.z);
    o[7] = f32_to_bf16_bits(b.w);
    *(ushort8*)(out + i) = o;
}

// ------------- transpose + convert: in [R][C] f32 -> out [C][R] bf16 --------
__global__ void k_transpose_convert(const float* __restrict__ in, __hip_bfloat16* __restrict__ out,
                                    int R, int C) {
    __shared__ float tile[32][33];
    int c0 = blockIdx.x * 32, r0 = blockIdx.y * 32;
    int tx = threadIdx.x, ty = threadIdx.y;  // block (32,8)
#pragma unroll
    for (int i = 0; i < 4; ++i) {
        int r = r0 + ty + i * 8;
        tile[ty + i * 8][tx] = in[(size_t)r * C + c0 + tx];
    }
    __syncthreads();
#pragma unroll
    for (int i = 0; i < 4; ++i) {
        int c = c0 + ty + i * 8;
        out[(size_t)c * R + r0 + tx] = __float2bfloat16(tile[tx][ty + i * 8]);
    }
}

// ------------- transpose v slice of qkv (bf16): vT[hd][t] = qkv[t][4096+hd] --
__global__ void k_transpose_v(const __hip_bfloat16* __restrict__ qkv, __hip_bfloat16* __restrict__ vT) {
    __shared__ __hip_bfloat16 tile[32][33];
    int c0 = blockIdx.x * 32, t0 = blockIdx.y * 32;
    int tx = threadIdx.x, ty = threadIdx.y;  // block (32,8)
#pragma unroll
    for (int i = 0; i < 4; ++i) {
        int t = t0 + ty + i * 8;
        tile[ty + i * 8][tx] = qkv[(size_t)t * N3E + 2 * E_DIM + c0 + tx];
    }
    __syncthreads();
#pragma unroll
    for (int i = 0; i < 4; ++i) {
        int c = c0 + ty + i * 8;
        vT[(size_t)c * S_DIM + t0 + tx] = tile[tx][ty + i * 8];
    }
}

// ======================= 256x256 deep-pipelined GEMM =========================
// C = A * Bt^T + bias.  A [M,K] bf16 row-major, Bt [N,K] bf16 row-major.
// BK=32, 4 LDS buffers (128 KB), 8 waves (2Mx4N), 2 phases per K-tile,
// stage tile t+3 during tile t, counted vmcnt(8) per tile (never 0 in steady
// state), raw s_barrier, setprio around MFMA clusters.
// LDS swizzle: 16B-slot ^= (row>>1)&3 (both-sides: inverse-swz global source,
// swz ds_read) -> worst 2-way bank aliasing (free).
// EPI==1: outB[M,N] bf16 (qkv); k/v cache f32 slices into outF at +4M/+8M.
template <int EPI>
__global__ __launch_bounds__(512, 2) void k_gemm256(const __hip_bfloat16* __restrict__ A,
                                                    const __hip_bfloat16* __restrict__ Bt,
                                                    const float* __restrict__ bias,
                                                    float* __restrict__ outF,
                                                    __hip_bfloat16* __restrict__ outB,
                                                    int M, int N, int K) {
    __shared__ __hip_bfloat16 As[4][256 * 32];
    __shared__ __hip_bfloat16 Bs[4][256 * 32];

    const int tid = threadIdx.x;
    const int w = tid >> 6, lane = tid & 63;
    const int lg = lane >> 4, l16 = lane & 15;
    const int wr = w >> 2, wc = w & 3;  // wave grid 2 (M) x 4 (N)
    const int m0 = blockIdx.y * 256, n0 = blockIdx.x * 256;
    const int NT = K >> 5;  // K-tiles of 32

    // --- staging constants: thread covers 16B chunk (row=tid>>2, slot=tid&3),
    // rows p*128+... for phase p; global col16 pre-inverse-swizzled.
    const int srow = tid >> 2;
    const int scol = ((tid & 3) ^ ((tid >> 3) & 3)) * 8;
    const __hip_bfloat16* aB = A + (size_t)(m0 + srow) * K + scol;
    const __hip_bfloat16* bB = Bt + (size_t)(n0 + srow) * K + scol;
    const size_t rstep = (size_t)128 * K;

#define STAGE(u, p)                                                                                   \
    do {                                                                                              \
        __builtin_amdgcn_global_load_lds(                                                             \
            (const __attribute__((address_space(1))) void*)(aB + (p) * rstep + (u) * 32),             \
            (__attribute__((address_space(3))) void*)(&As[(u) & 3][(p) * 4096 + tid * 8]), 16, 0, 0); \
        __builtin_amdgcn_global_load_lds(                                                             \
            (const __attribute__((address_space(1))) void*)(bB + (p) * rstep + (u) * 32),             \
            (__attribute__((address_space(3))) void*)(&Bs[(u) & 3][(p) * 4096 + tid * 8]), 16, 0, 0); \
    } while (0)

    f32x4 acc[8][4];
#pragma unroll
    for (int i = 0; i < 8; ++i)
#pragma unroll
        for (int j = 0; j < 4; ++j) acc[i][j] = {0.f, 0.f, 0.f, 0.f};

    // prologue: stage tiles 0,1,2 (12 issues); retire tile 0 (keep 8 in flight)
    STAGE(0, 0); STAGE(0, 1);
    STAGE(1, 0); STAGE(1, 1);
    STAGE(2, 0); STAGE(2, 1);
    asm volatile("s_waitcnt vmcnt(8)" ::: "memory");
    __builtin_amdgcn_s_barrier();

    short8 af[4], bf[4];
    for (int t = 0; t < NT; ++t) {
        const int cur = t & 3;
        const int u = t + 3;
        // ---- phase 0: frags (A rows mh=0, all B) + stage + 16 MFMA ----
#pragma unroll
        for (int i = 0; i < 4; ++i) {
            int arow = wr * 128 + i * 16 + l16;
            af[i] = *(const short8*)&As[cur][arow * 32 + ((lg ^ ((arow >> 1) & 3)) * 8)];
            int brow = wc * 64 + i * 16 + l16;
            bf[i] = *(const short8*)&Bs[cur][brow * 32 + ((lg ^ ((brow >> 1) & 3)) * 8)];
        }
        if (u < NT) STAGE(u, 0);
        __builtin_amdgcn_s_barrier();
        __builtin_amdgcn_s_setprio(1);
#pragma unroll
        for (int mi = 0; mi < 4; ++mi)
#pragma unroll
            for (int ni = 0; ni < 4; ++ni)
                acc[mi][ni] = __builtin_amdgcn_mfma_f32_16x16x32_bf16(af[mi], bf[ni], acc[mi][ni], 0, 0, 0);
        __builtin_amdgcn_s_setprio(0);
        __builtin_amdgcn_s_barrier();
        // ---- phase 1: frags (A rows mh=1) + stage + 16 MFMA ----
#pragma unroll
        for (int i = 0; i < 4; ++i) {
            int arow = wr * 128 + 64 + i * 16 + l16;
            af[i] = *(const short8*)&As[cur][arow * 32 + ((lg ^ ((arow >> 1) & 3)) * 8)];
        }
        if (u < NT) STAGE(u, 1);
        __builtin_amdgcn_s_barrier();
        __builtin_amdgcn_s_setprio(1);
#pragma unroll
        for (int mi = 0; mi < 4; ++mi)
#pragma unroll
            for (int ni = 0; ni < 4; ++ni)
                acc[4 + mi][ni] = __builtin_amdgcn_mfma_f32_16x16x32_bf16(af[mi], bf[ni], acc[4 + mi][ni], 0, 0, 0);
        __builtin_amdgcn_s_setprio(0);
        // ---- end of tile: counted retire of tile t+1's loads, then barrier --
        __builtin_amdgcn_sched_barrier(0);
        if (t < NT - 3)
            asm volatile("s_waitcnt vmcnt(8)" ::: "memory");
        else if (t == NT - 3)
            asm volatile("s_waitcnt vmcnt(4)" ::: "memory");
        else if (t == NT - 2)
            asm volatile("s_waitcnt vmcnt(0)" ::: "memory");
        __builtin_amdgcn_sched_barrier(0);
        __builtin_amdgcn_s_barrier();
    }
#undef STAGE

    // ---- epilogue ----
    const size_t OFF_K = (size_t)S_DIM * E_DIM;
    const size_t OFF_V = 2 * (size_t)S_DIM * E_DIM;
#pragma unroll
    for (int ni = 0; ni < 4; ++ni) {
        int jcol = n0 + wc * 64 + ni * 16 + l16;
        float bj = bias[jcol];
#pragma unroll
        for (int mi = 0; mi < 8; ++mi) {
#pragma unroll
            for (int r = 0; r < 4; ++r) {
                int s = m0 + wr * 128 + mi * 16 + lg * 4 + r;
                float v = acc[mi][ni][r] + bj;
                if (EPI == 1) {
                    outB[(size_t)s * N + jcol] = __float2bfloat16(v);
                    if (jcol >= 2 * E_DIM) {
                        outF[OFF_V + (size_t)s * E_DIM + (jcol - 2 * E_DIM)] = v;
                    } else if (jcol >= E_DIM) {
                        outF[OFF_K + (size_t)s * E_DIM + (jcol - E_DIM)] = v;
                    }
                } else {
                    outF[(size_t)s * N + jcol] = v;
                }
            }
        }
    }
}

// ---------------- m97-style 128x128 bf16 GEMM (kept for GEMM2) --------------
template <int EPI>
__global__ __launch_bounds__(256) void k_gemm(const __hip_bfloat16* __restrict__ A,
                                              const __hip_bfloat16* __restrict__ Bt,
                                              const float* __restrict__ bias,
                                              float* __restrict__ outF,
                                              __hip_bfloat16* __restrict__ outB,
                                              int M, int N, int K) {
    __shared__ __hip_bfloat16 As[128 * 32];
    __shared__ __hip_bfloat16 Bs[128 * 32];
    const int w = threadIdx.x >> 6, lane = threadIdx.x & 63;
    const int lg = lane >> 4, l16 = lane & 15;
    const int wr = w >> 1, wc = w & 1;
    const int m0 = blockIdx.y * 128, n0 = blockIdx.x * 128;

    f32x4 acc[4][4];
#pragma unroll
    for (int i = 0; i < 4; ++i)
#pragma unroll
        for (int j = 0; j < 4; ++j) acc[i][j] = {0.f, 0.f, 0.f, 0.f};

    const int scol = (lane & 3) * 8;

    for (int k0 = 0; k0 < K; k0 += 32) {
#pragma unroll
        for (int j = 0; j < 2; ++j) {
            int c = w * 2 + j;
            int row = c * 16 + (lane >> 2);
            const __hip_bfloat16* ga = A + (size_t)(m0 + row) * K + k0 + scol;
            const __hip_bfloat16* gb = Bt + (size_t)(n0 + row) * K + k0 + scol;
            __builtin_amdgcn_global_load_lds((const __attribute__((address_space(1))) void*)ga,
                                             (__attribute__((address_space(3))) void*)(As + c * 512),
                                             16, 0, 0);
            __builtin_amdgcn_global_load_lds((const __attribute__((address_space(1))) void*)gb,
                                             (__attribute__((address_space(3))) void*)(Bs + c * 512),
                                             16, 0, 0);
        }
        __syncthreads();
        short8 af[4], bfr[4];
#pragma unroll
        for (int mi = 0; mi < 4; ++mi)
            af[mi] = *(const short8*)&As[(wr * 64 + mi * 16 + l16) * 32 + lg * 8];
#pragma unroll
        for (int ni = 0; ni < 4; ++ni)
            bfr[ni] = *(const short8*)&Bs[(wc * 64 + ni * 16 + l16) * 32 + lg * 8];
#pragma unroll
        for (int mi = 0; mi < 4; ++mi)
#pragma unroll
            for (int ni = 0; ni < 4; ++ni)
                acc[mi][ni] = __builtin_amdgcn_mfma_f32_16x16x32_bf16(af[mi], bfr[ni], acc[mi][ni], 0, 0, 0);
        __syncthreads();
    }

    const size_t OFF_K = (size_t)S_DIM * E_DIM;
    const size_t OFF_V = 2 * (size_t)S_DIM * E_DIM;
#pragma unroll
    for (int ni = 0; ni < 4; ++ni) {
        int jcol = n0 + wc * 64 + ni * 16 + l16;
        float bj = bias[jcol];
#pragma unroll
        for (int mi = 0; mi < 4; ++mi) {
#pragma unroll
            for (int r = 0; r < 4; ++r) {
                int s = m0 + wr * 64 + mi * 16 + lg * 4 + r;
                float v = acc[mi][ni][r] + bj;
                if (EPI == 1) {
                    outB[(size_t)s * N + jcol] = __float2bfloat16(v);
                    if (jcol >= 2 * E_DIM) {
                        outF[OFF_V + (size_t)s * E_DIM + (jcol - 2 * E_DIM)] = v;
                    } else if (jcol >= E_DIM) {
                        outF[OFF_K + (size_t)s * E_DIM + (jcol - E_DIM)] = v;
                    }
                } else {
                    outF[(size_t)s * N + jcol] = v;
                }
            }
        }
    }
}

// ---------------- flash attention (causal), one head x 64 q-rows per block --
__global__ __launch_bounds__(256) void k_attn(const __hip_bfloat16* __restrict__ qkv,  // [S][6144]
                                              const __hip_bfloat16* __restrict__ vT,   // [2048][2048] row=h*128+d
                                              __hip_bfloat16* __restrict__ concat) {   // [S][2048]
    const int h = blockIdx.y;
    const int q0 = blockIdx.x * 64;
    const int tid = threadIdx.x;
    const int w = tid >> 6, lane = tid & 63;
    const int lg = lane >> 4, l16 = lane & 15;
    const int sbase = q0 + w * 16;
    const float scale = 0.08838834764831845f;  // 1/sqrt(128)

    __shared__ __hip_bfloat16 Ks[2][64 * 128];   // [t][d], swizzled
    __shared__ __hip_bfloat16 Vs[2][128 * 64];   // [d][t], swizzled
    __shared__ __hip_bfloat16 plds[4][16 * 80];

    short8 qa[4];
#pragma unroll
    for (int kc = 0; kc < 4; ++kc)
        qa[kc] = *(const short8*)&qkv[(size_t)(sbase + l16) * N3E + h * D_HEAD + kc * 32 + lg * 8];

    f32x4 O[8];
#pragma unroll
    for (int i = 0; i < 8; ++i) O[i] = {0.f, 0.f, 0.f, 0.f};
    float m_r[4], l_r[4];
#pragma unroll
    for (int r = 0; r < 4; ++r) {
        m_r[r] = -1e30f;
        l_r[r] = 0.f;
    }

    auto stage = [&](int buf, int t0) {
#pragma unroll
        for (int j = 0; j < 4; ++j) {
            int kr = j * 16 + w * 4 + (lane >> 4);
            int ks16 = (lane & 15) ^ (kr & 7);
            const __hip_bfloat16* gk = qkv + (size_t)(t0 + kr) * N3E + E_DIM + h * D_HEAD + ks16 * 8;
            __builtin_amdgcn_global_load_lds((const __attribute__((address_space(1))) void*)gk,
                                             (__attribute__((address_space(3))) void*)(&Ks[buf][j * 2048 + w * 512]),
                                             16, 0, 0);
            int vd = j * 32 + w * 8 + (lane >> 3);
            int vs16 = (lane & 7) ^ (vd & 7);
            const __hip_bfloat16* gv = vT + (size_t)(h * D_HEAD + vd) * S_DIM + t0 + vs16 * 8;
            __builtin_amdgcn_global_load_lds((const __attribute__((address_space(1))) void*)gv,
                                             (__attribute__((address_space(3))) void*)(&Vs[buf][j * 2048 + w * 512]),
                                             16, 0, 0);
        }
    };

    const int ntiles = q0 / 64 + 1;
    stage(0, 0);
    int cur = 0;

    for (int it = 0; it < ntiles; ++it) {
        const int t0 = it * 64;
        __syncthreads();
        if (it + 1 < ntiles) stage(cur ^ 1, (it + 1) * 64);
        const bool diag = (t0 == q0);

        f32x4 sc[4];
#pragma unroll
        for (int f = 0; f < 4; ++f) {
            sc[f] = {0.f, 0.f, 0.f, 0.f};
            int r = f * 16 + l16;
#pragma unroll
            for (int kc = 0; kc < 4; ++kc) {
                int ce = (kc * 32 + lg * 8) ^ ((r & 7) << 3);
                short8 kb = *(const short8*)&Ks[cur][r * 128 + ce];
                sc[f] = __builtin_amdgcn_mfma_f32_16x16x32_bf16(qa[kc], kb, sc[f], 0, 0, 0);
            }
        }

        float tmax[4];
#pragma unroll
        for (int r = 0; r < 4; ++r) tmax[r] = -1e30f;
#pragma unroll
        for (int f = 0; f < 4; ++f) {
#pragma unroll
            for (int r = 0; r < 4; ++r) {
                float v = sc[f][r] * scale;
                if (diag) {
                    int t = t0 + f * 16 + l16;
                    int s = sbase + lg * 4 + r;
                    if (t > s) v = -1e30f;
                }
                sc[f][r] = v;
                tmax[r] = fmaxf(tmax[r], v);
            }
        }
#pragma unroll
        for (int off = 1; off < 16; off <<= 1) {
#pragma unroll
            for (int r = 0; r < 4; ++r) tmax[r] = fmaxf(tmax[r], __shfl_xor(tmax[r], off, 64));
        }
        float alpha[4];
#pragma unroll
        for (int r = 0; r < 4; ++r) {
            float mnew = fmaxf(m_r[r], tmax[r]);
            alpha[r] = __expf(m_r[r] - mnew);
            m_r[r] = mnew;
        }
        float rsum[4] = {0.f, 0.f, 0.f, 0.f};
#pragma unroll
        for (int f = 0; f < 4; ++f) {
#pragma unroll
            for (int r = 0; r < 4; ++r) {
                float p = __expf(sc[f][r] - m_r[r]);
                sc[f][r] = p;
                rsum[r] += p;
            }
        }
#pragma unroll
        for (int off = 1; off < 16; off <<= 1) {
#pragma unroll
            for (int r = 0; r < 4; ++r) rsum[r] += __shfl_xor(rsum[r], off, 64);
        }
#pragma unroll
        for (int r = 0; r < 4; ++r) l_r[r] = l_r[r] * alpha[r] + rsum[r];
#pragma unroll
        for (int f2 = 0; f2 < 8; ++f2)
#pragma unroll
            for (int r = 0; r < 4; ++r) O[f2][r] *= alpha[r];

#pragma unroll
        for (int f = 0; f < 4; ++f)
#pragma unroll
            for (int r = 0; r < 4; ++r)
                plds[w][(lg * 4 + r) * 80 + f * 16 + l16] = __float2bfloat16(sc[f][r]);
        short8 pa[2];
#pragma unroll
        for (int tc = 0; tc < 2; ++tc)
            pa[tc] = *(const short8*)&plds[w][l16 * 80 + tc * 32 + lg * 8];

#pragma unroll
        for (int f2 = 0; f2 < 8; ++f2) {
            int d = f2 * 16 + l16;
#pragma unroll
            for (int tc = 0; tc < 2; ++tc) {
                int ce = (tc * 32 + lg * 8) ^ ((d & 7) << 3);
                short8 vb = *(const short8*)&Vs[cur][d * 64 + ce];
                O[f2] = __builtin_amdgcn_mfma_f32_16x16x32_bf16(pa[tc], vb, O[f2], 0, 0, 0);
            }
        }
        cur ^= 1;
    }

#pragma unroll
    for (int f2 = 0; f2 < 8; ++f2) {
#pragma unroll
        for (int r = 0; r < 4; ++r) {
            int s = sbase + lg * 4 + r;
            float v = O[f2][r] / l_r[r];
            concat[(size_t)s * E_DIM + h * D_HEAD + f2 * 16 + l16] = __float2bfloat16(v);
        }
    }
}

extern "C" void kernel_launch(void* const* d_in, const int* in_sizes, int n_in,
                              void* d_out, int out_size, void* d_ws, size_t ws_size,
                              hipStream_t stream) {
    const float* x = (const float*)d_in[0];
    const float* W_attn = (const float*)d_in[1];
    const float* b_attn = (const float*)d_in[2];
    const float* W_proj = (const float*)d_in[3];
    const float* b_proj = (const float*)d_in[4];
    float* out = (float*)d_out;

    __hip_bfloat16* xb = (__hip_bfloat16*)d_ws;                    // 2048x2048
    __hip_bfloat16* WaT = xb + (size_t)S_DIM * E_DIM;              // 6144x2048
    __hip_bfloat16* WpT = WaT + (size_t)N3E * E_DIM;               // 2048x2048
    __hip_bfloat16* qkvb = WpT + (size_t)E_DIM * E_DIM;            // 2048x6144
    __hip_bfloat16* vT = qkvb + (size_t)S_DIM * N3E;               // 2048x2048
    __hip_bfloat16* concat = xb;                                   // alias

    k_convert<<<dim3((S_DIM * E_DIM) / (256 * 8)), dim3(256), 0, stream>>>(x, xb, S_DIM * E_DIM);
    k_transpose_convert<<<dim3(N3E / 32, E_DIM / 32), dim3(32, 8), 0, stream>>>(W_attn, WaT, E_DIM, N3E);
    k_transpose_convert<<<dim3(E_DIM / 32, E_DIM / 32), dim3(32, 8), 0, stream>>>(W_proj, WpT, E_DIM, E_DIM);
    // GEMM1: 256^2 deep-pipelined kernel, grid 24x8 = 192 blocks
    k_gemm256<1><<<dim3(N3E / 256, S_DIM / 256), dim3(512), 0, stream>>>(xb, WaT, b_attn, out, qkvb,
                                                                         S_DIM, N3E, E_DIM);
    k_transpose_v<<<dim3(E_DIM / 32, S_DIM / 32), dim3(32, 8), 0, stream>>>(qkvb, vT);
    k_attn<<<dim3(S_DIM / 64, H_NUM), dim3(256), 0, stream>>>(qkvb, vT, concat);
    // GEMM2: m97 128^2 kernel (256 blocks)
    k_gemm<0><<<dim3(E_DIM / 128, S_DIM / 128), dim3(256), 0, stream>>>(concat, WpT, b_proj, out,
                                                                        nullptr, S_DIM, E_DIM, E_DIM);
}